// Round 6
// baseline (50.209 us; speedup 1.0000x reference)
//
#include <hip/hip_runtime.h>

#define NROT 256
#define NB   8192
#define TBL_ROUNDS 264   // 255 real rounds + identity padding for prefetch ring

typedef _Float16 f16;
typedef _Float16 f16x4 __attribute__((ext_vector_type(4)));
typedef _Float16 f16x8 __attribute__((ext_vector_type(8)));
typedef float    f32x4 __attribute__((ext_vector_type(4)));

// ---------------------------------------------------------------------------
// Workspace layout (bytes):
//   [0,       270336)    cs table: 264 rounds x 128 x float2 {c, s_signed}
//   [270336,  1318912)   Rg: 4 group products (4 x 256x256 f32)
//   [1318912, 1843200)   Pg: 2 level-1 products (2 x 256x256 f32)
//   [1843200, 1974272)   Rh: merged R in fp16 (256x256)
// ---------------------------------------------------------------------------

// ---------------------------------------------------------------------------
// K1: cs table {c, s_signed} per (round, position-pair k).
// Position-space formulation: round r rotates positions (k, 255-k); if the
// value at position k is the LARGER row index, the reference's role swap is
// exactly s -> -s in the uniform update -- fold it into the table.
// Rounds >= 255: identity (c=1, s=0).
// ---------------------------------------------------------------------------
__global__ void k_prep(const float* __restrict__ thetas, float2* __restrict__ cs) {
    int idx = blockIdx.x * 256 + threadIdx.x;
    if (idx >= TBL_ROUNDS * 128) return;
    int r = idx >> 7;
    int k = idx & 127;
    if (r >= 255) { cs[idx] = make_float2(1.0f, 0.0f); return; }
    int i, j;
    bool swapped = false;
    if (k == 0) {
        i = 0;
        j = 255 - r;
    } else {
        int m1 = k - 1 - r;   if (m1 < 0) m1 += 255;
        int m2 = 254 - k - r; if (m2 < 0) m2 += 255;
        int v1 = m1 + 1, v2 = m2 + 1;   // v1 = row at pos k, v2 = row at pos 255-k
        swapped = v1 > v2;
        i = swapped ? v2 : v1;
        j = swapped ? v1 : v2;
    }
    int tix = i * 256 - (i * (i + 1)) / 2 + (j - i - 1);
    float th = thetas[tix];
    float s, c;
    sincosf(th, &s, &c);
    cs[idx] = make_float2(c, swapped ? -s : s);
}

// ---------------------------------------------------------------------------
// K2: partial rotation products, 4 groups of 64 rounds, REGISTER-RESIDENT.
// Positions mapped to lanes: lane l holds pos A0=2l, A1=2l+1, B1=254-2l,
// B0=255-2l  ->  every round's rotation pairs (A0,B0),(A1,B1) are lane-local
// VALU.  Inter-round shift (pos p -> p+1, pos 0 pinned) is two shfl-by-1:
//   A0(l) <- nA1(l-1)   [l=0: nA0 stays, pos 0]
//   A1(l) <- nA0(l)     [l=0: nB0, pos 255 -> pos 1]
//   B0(l) <- nB1(l)
//   B1(l) <- nB0(l+1)   [l=63: nA1, pos 127 -> pos 128]
// Chain/round ~ 2-deep FMA + 1 shfl (~50 cyc) vs ~200 for the LDS version.
// Depth-4 cs prefetch ring (1 float4 = 2 pairs per lane per round).
// ---------------------------------------------------------------------------
__device__ __forceinline__ int rowOf(int p, int R) {
    if (p == 0) return 0;
    int m = (p - 1 - R) % 255;
    if (m < 0) m += 255;
    return m + 1;
}

__global__ __launch_bounds__(64) void k_rot(const float4* __restrict__ csf4,
                                            float* __restrict__ Rg) {
    int l    = threadIdx.x;                  // 0..63, one wave per block
    int grp  = blockIdx.y;                   // 0..3
    int c    = blockIdx.x;                   // this block's column
    int ROFF = grp * 64;

    int pA0 = 2 * l, pA1 = 2 * l + 1, pB1 = 254 - 2 * l, pB0 = 255 - 2 * l;

    // init: val[p] = e_c[arr_ROFF[p]]
    float A0 = (rowOf(pA0, ROFF) == c) ? 1.0f : 0.0f;
    float A1 = (rowOf(pA1, ROFF) == c) ? 1.0f : 0.0f;
    float B1 = (rowOf(pB1, ROFF) == c) ? 1.0f : 0.0f;
    float B0 = (rowOf(pB0, ROFF) == c) ? 1.0f : 0.0f;

    float4 ring[4];
#pragma unroll
    for (int d = 0; d < 4; ++d) ring[d] = csf4[(ROFF + d) * 64 + l];

#pragma unroll 4
    for (int it = 0; it < 64; ++it) {
        const int slot = it & 3;             // static under unroll-4
        float4 CS = ring[slot];
        ring[slot] = csf4[(ROFF + it + 4) * 64 + l];  // pads are identity

        float nA0 = CS.x * A0 - CS.y * B0;
        float nB0 = CS.y * A0 + CS.x * B0;
        float nA1 = CS.z * A1 - CS.w * B1;
        float nB1 = CS.w * A1 + CS.z * B1;

        float upA1 = __shfl_up(nA1, 1);      // lane l gets lane l-1's nA1
        float dnB0 = __shfl_down(nB0, 1);    // lane l gets lane l+1's nB0

        A0 = (l == 0)  ? nA0 : upA1;
        A1 = (l == 0)  ? nB0 : nA0;
        B0 = nB1;
        B1 = (l == 63) ? nA1 : dnB0;
    }

    // output: row = arr_{ROFF+64}[p]
    int R = ROFF + 64;
    float* Rout = Rg + grp * (256 * 256);
    Rout[rowOf(pA0, R) * 256 + c] = A0;
    Rout[rowOf(pA1, R) * 256 + c] = A1;
    Rout[rowOf(pB1, R) * 256 + c] = B1;
    Rout[rowOf(pB0, R) * 256 + c] = B0;
}

// ---------------------------------------------------------------------------
// K3a: level-1 merge, batched: P_z = G_{2z+1} * G_{2z}  (z = blockIdx.z).
// Tiled 16 rows x 64 cols per block (grid 4x16x2 = 128 blocks): V-rows in
// LDS (padded stride 260 -> conflict-free 4-addr broadcast), A streamed
// (256B/wave, L1-broadcast across row-groups).  ~10 MB total traffic vs the
// old row-vector merge's 192 MB.
// ---------------------------------------------------------------------------
__device__ __forceinline__ void merge_tile(const float* __restrict__ B,
                                           const float* __restrict__ A,
                                           float (*Vs)[260], int t,
                                           int r0, int c0, float4* accp) {
    // stage V = B rows [r0, r0+16) x 256  (1024 float4, 4 per thread)
#pragma unroll
    for (int p = 0; p < 4; ++p) {
        int idx = t + 256 * p;               // 0..1023
        int row = idx >> 6;
        int k4  = (idx & 63) * 4;
        *(float4*)&Vs[row][k4] = *(const float4*)(B + (r0 + row) * 256 + k4);
    }
    __syncthreads();

    int r  = t >> 4;                         // 0..15
    int c4 = (t & 15) * 4;                   // 0..60
    float4 acc = make_float4(0.f, 0.f, 0.f, 0.f);
#pragma unroll 8
    for (int k = 0; k < 256; ++k) {
        float  av = Vs[r][k];
        float4 a  = *(const float4*)(A + k * 256 + c0 + c4);
        acc.x += av * a.x; acc.y += av * a.y;
        acc.z += av * a.z; acc.w += av * a.w;
    }
    *accp = acc;
}

__global__ __launch_bounds__(256) void k_mergeL1(const float* __restrict__ Rg,
                                                 float* __restrict__ Pg) {
    __shared__ float Vs[16][260];
    int t  = threadIdx.x;
    int c0 = blockIdx.x * 64;
    int r0 = blockIdx.y * 16;
    int z  = blockIdx.z;
    const float* A = Rg + (2 * z) * 65536;       // applied first
    const float* B = Rg + (2 * z + 1) * 65536;   // applied second (left)
    float4 acc;
    merge_tile(B, A, Vs, t, r0, c0, &acc);
    int r = t >> 4, c4 = (t & 15) * 4;
    *(float4*)(Pg + z * 65536 + (r0 + r) * 256 + c0 + c4) = acc;
}

// K3b: final merge R = P1 * P0, emit fp16 for the MFMA gemm.
__global__ __launch_bounds__(256) void k_mergeL2(const float* __restrict__ Pg,
                                                 f16* __restrict__ Rh) {
    __shared__ float Vs[16][260];
    int t  = threadIdx.x;
    int c0 = blockIdx.x * 64;
    int r0 = blockIdx.y * 16;
    const float* A = Pg;                         // P0
    const float* B = Pg + 65536;                 // P1 (left)
    float4 acc;
    merge_tile(B, A, Vs, t, r0, c0, &acc);
    int r = t >> 4, c4 = (t & 15) * 4;
    f16x4 h = { (f16)acc.x, (f16)acc.y, (f16)acc.z, (f16)acc.w };
    *(f16x4*)(Rh + (r0 + r) * 256 + c0 + c4) = h;
}

// ---------------------------------------------------------------------------
// K4: out = R * X via FP16 MFMA (mfma_f32_16x16x32_f16, fp32 accumulate).
// Unchanged from round 5 (verified correct).
// ---------------------------------------------------------------------------
__global__ __launch_bounds__(512) void k_gemm(const f16* __restrict__ Rh,
                                              const float* __restrict__ X,
                                              float* __restrict__ out) {
    __shared__ float Xf[256][32];                    // 32 KB fp32 staging
    __shared__ __align__(16) f16 Xh[32 * 256];       // 16 KB fp16 k-major
    int t  = threadIdx.x;
    int w  = t >> 6;                                 // wave 0..7
    int l  = t & 63;
    int n0 = blockIdx.x * 32;

    // phase A: global -> Xf (coalesced float4)
#pragma unroll
    for (int p = 0; p < 4; ++p) {
        int idx = t + 512 * p;                       // 0..2047
        int n4  = idx & 7;
        int k   = idx >> 3;
        *(float4*)&Xf[k][n4 * 4] =
            *(const float4*)(X + (size_t)k * NB + n0 + n4 * 4);
    }
    __syncthreads();

    // phase B: Xf -> fp16 k-major swizzled Xh
    {
        int n  = t & 31;
        int k0 = (t >> 5) * 16;
        f16x8 h0, h1;
#pragma unroll
        for (int u = 0; u < 8; ++u) h0[u] = (f16)Xf[k0 + u][n];
#pragma unroll
        for (int u = 0; u < 8; ++u) h1[u] = (f16)Xf[k0 + 8 + u][n];
        int xv = (n & 7) * 8;
        *(f16x8*)&Xh[n * 256 + ((k0    ) ^ xv)] = h0;
        *(f16x8*)&Xh[n * 256 + ((k0 + 8) ^ xv)] = h1;
    }
    __syncthreads();

    f32x4 acc[2][2];
#pragma unroll
    for (int r = 0; r < 2; ++r)
#pragma unroll
        for (int c = 0; c < 2; ++c) acc[r][c] = (f32x4){0.f, 0.f, 0.f, 0.f};

    int lm = l & 15;
    int g  = l >> 4;
    int xv = (lm & 7) * 8;
#pragma unroll
    for (int s = 0; s < 8; ++s) {
        int koff = s * 32 + 8 * g;
        f16x8 a0 = *(const f16x8*)(Rh + (32 * w + lm) * 256 + koff);
        f16x8 a1 = *(const f16x8*)(Rh + (32 * w + 16 + lm) * 256 + koff);
        f16x8 b0 = *(const f16x8*)&Xh[lm * 256        + (koff ^ xv)];
        f16x8 b1 = *(const f16x8*)&Xh[(16 + lm) * 256 + (koff ^ xv)];
        acc[0][0] = __builtin_amdgcn_mfma_f32_16x16x32_f16(a0, b0, acc[0][0], 0, 0, 0);
        acc[0][1] = __builtin_amdgcn_mfma_f32_16x16x32_f16(a0, b1, acc[0][1], 0, 0, 0);
        acc[1][0] = __builtin_amdgcn_mfma_f32_16x16x32_f16(a1, b0, acc[1][0], 0, 0, 0);
        acc[1][1] = __builtin_amdgcn_mfma_f32_16x16x32_f16(a1, b1, acc[1][1], 0, 0, 0);
    }

    // C/D layout: col = lane&15, row = (lane>>4)*4 + reg
#pragma unroll
    for (int r = 0; r < 2; ++r)
#pragma unroll
        for (int c = 0; c < 2; ++c)
#pragma unroll
            for (int q = 0; q < 4; ++q)
                out[(size_t)(32 * w + 16 * r + 4 * g + q) * NB + n0 + 16 * c + lm] =
                    acc[r][c][q];
}

// ---------------------------------------------------------------------------
extern "C" void kernel_launch(void* const* d_in, const int* in_sizes, int n_in,
                              void* d_out, int out_size, void* d_ws, size_t ws_size,
                              hipStream_t stream) {
    const float* X      = (const float*)d_in[0];
    const float* thetas = (const float*)d_in[1];
    float* out = (float*)d_out;
    char*  ws  = (char*)d_ws;

    float2* cs   = (float2*)ws;
    float4* csf4 = (float4*)ws;
    float*  Rg   = (float*)(ws + 270336);
    float*  Pg   = (float*)(ws + 1318912);
    f16*    Rh   = (f16*)(ws + 1843200);

    k_prep   <<<dim3(132),      dim3(256), 0, stream>>>(thetas, cs);
    k_rot    <<<dim3(256, 4),   dim3(64),  0, stream>>>(csf4, Rg);
    k_mergeL1<<<dim3(4, 16, 2), dim3(256), 0, stream>>>(Rg, Pg);
    k_mergeL2<<<dim3(4, 16),    dim3(256), 0, stream>>>(Pg, Rh);
    k_gemm   <<<dim3(256),      dim3(512), 0, stream>>>(Rh, X, out);
}

// Round 7
// 39.411 us; speedup vs baseline: 1.2740x; 1.2740x over previous
//
#include <hip/hip_runtime.h>

#define NROT 256
#define NB   8192
#define TBL_ROUNDS 264   // 255 real rounds + identity padding for prefetch ring

typedef _Float16 f16;
typedef _Float16 f16x8 __attribute__((ext_vector_type(8)));
typedef float    f32x4 __attribute__((ext_vector_type(4)));

// ---------------------------------------------------------------------------
// Workspace layout (bytes):
//   [0,       270336)    cs table: 264 rounds x 128 x float2 {c, s_signed}
//   [270336,  1318912)   Rg: 4 group products (4 x 256x256 f32)
//   [1318912, 1449984)   Rh: merged R in fp16 (256x256)
// ---------------------------------------------------------------------------

// ---------------------------------------------------------------------------
// K1: cs table {c, s_signed} per (round, position-pair k).
// Position-space: round r rotates positions (k, 255-k); if the value at pos k
// is the LARGER row index, the reference's role swap is exactly s -> -s.
// Rounds >= 255: identity (c=1, s=0).
// ---------------------------------------------------------------------------
__global__ void k_prep(const float* __restrict__ thetas, float2* __restrict__ cs) {
    int idx = blockIdx.x * 256 + threadIdx.x;
    if (idx >= TBL_ROUNDS * 128) return;
    int r = idx >> 7;
    int k = idx & 127;
    if (r >= 255) { cs[idx] = make_float2(1.0f, 0.0f); return; }
    int i, j;
    bool swapped = false;
    if (k == 0) {
        i = 0;
        j = 255 - r;
    } else {
        int m1 = k - 1 - r;   if (m1 < 0) m1 += 255;
        int m2 = 254 - k - r; if (m2 < 0) m2 += 255;
        int v1 = m1 + 1, v2 = m2 + 1;   // v1 = row at pos k, v2 = row at pos 255-k
        swapped = v1 > v2;
        i = swapped ? v2 : v1;
        j = swapped ? v1 : v2;
    }
    int tix = i * 256 - (i * (i + 1)) / 2 + (j - i - 1);
    float th = thetas[tix];
    float s, c;
    sincosf(th, &s, &c);
    cs[idx] = make_float2(c, swapped ? -s : s);
}

// ---------------------------------------------------------------------------
// K2: partial rotation products, 4 groups of 64 rounds, REGISTER-RESIDENT
// (verified correct in round 6).  Lane l holds positions A0=2l, A1=2l+1,
// B1=254-2l, B0=255-2l; rotations are lane-local VALU; the inter-round
// position shift is two shfl-by-1.  Depth-4 cs prefetch ring.
// ---------------------------------------------------------------------------
__device__ __forceinline__ int rowOf(int p, int R) {
    if (p == 0) return 0;
    int m = (p - 1 - R) % 255;
    if (m < 0) m += 255;
    return m + 1;
}

__global__ __launch_bounds__(64) void k_rot(const float4* __restrict__ csf4,
                                            float* __restrict__ Rg) {
    int l    = threadIdx.x;                  // 0..63, one wave per block
    int grp  = blockIdx.y;                   // 0..3
    int c    = blockIdx.x;                   // this block's column
    int ROFF = grp * 64;

    int pA0 = 2 * l, pA1 = 2 * l + 1, pB1 = 254 - 2 * l, pB0 = 255 - 2 * l;

    float A0 = (rowOf(pA0, ROFF) == c) ? 1.0f : 0.0f;
    float A1 = (rowOf(pA1, ROFF) == c) ? 1.0f : 0.0f;
    float B1 = (rowOf(pB1, ROFF) == c) ? 1.0f : 0.0f;
    float B0 = (rowOf(pB0, ROFF) == c) ? 1.0f : 0.0f;

    float4 ring[4];
#pragma unroll
    for (int d = 0; d < 4; ++d) ring[d] = csf4[(ROFF + d) * 64 + l];

#pragma unroll 4
    for (int it = 0; it < 64; ++it) {
        const int slot = it & 3;             // static under unroll-4
        float4 CS = ring[slot];
        ring[slot] = csf4[(ROFF + it + 4) * 64 + l];  // pads are identity

        float nA0 = CS.x * A0 - CS.y * B0;
        float nB0 = CS.y * A0 + CS.x * B0;
        float nA1 = CS.z * A1 - CS.w * B1;
        float nB1 = CS.w * A1 + CS.z * B1;

        float upA1 = __shfl_up(nA1, 1);      // lane l gets lane l-1's nA1
        float dnB0 = __shfl_down(nB0, 1);    // lane l gets lane l+1's nB0

        A0 = (l == 0)  ? nA0 : upA1;
        A1 = (l == 0)  ? nB0 : nA0;
        B0 = nB1;
        B1 = (l == 63) ? nA1 : dnB0;
    }

    int R = ROFF + 64;
    float* Rout = Rg + grp * (256 * 256);
    Rout[rowOf(pA0, R) * 256 + c] = A0;
    Rout[rowOf(pA1, R) * 256 + c] = A1;
    Rout[rowOf(pB1, R) * 256 + c] = B1;
    Rout[rowOf(pB0, R) * 256 + c] = B0;
}

// ---------------------------------------------------------------------------
// K3: fused 3-stage merge  R = G3*G2*G1*G0, fp16 output (EXACT round-5 form:
// 256 blocks x 256 threads, 1 row/block, coalesced unique 1KB/wave A-loads,
// L2-BW-bound ~5.6us.  Round-6's tiled variant was issue/occupancy-bound:
// 4x redundant quarter-wave loads at <=1 block/CU cost ~+11us -- reverted).
// ---------------------------------------------------------------------------
__global__ __launch_bounds__(256) void k_merge4(const float* __restrict__ Rg,
                                                f16* __restrict__ Rh) {
    __shared__ float vcur[256];
    __shared__ float pacc[4][256];
    int t = threadIdx.x;
    int w = t >> 6;
    int l = t & 63;
    int r0 = blockIdx.x;

    if (t < 64)
        *(float4*)&vcur[t * 4] =
            *(const float4*)(Rg + 3 * 65536 + r0 * 256 + t * 4);
    __syncthreads();

    for (int g = 2; g >= 0; --g) {
        const float* A = Rg + g * 65536;
        int kbase = w * 64;
        float4 acc = make_float4(0.f, 0.f, 0.f, 0.f);
#pragma unroll 8
        for (int kk = 0; kk < 64; ++kk) {
            float  s = vcur[kbase + kk];
            float4 a = *(const float4*)(A + (kbase + kk) * 256 + l * 4);
            acc.x += s * a.x; acc.y += s * a.y;
            acc.z += s * a.z; acc.w += s * a.w;
        }
        *(float4*)&pacc[w][l * 4] = acc;
        __syncthreads();
        if (t < 64) {
            float4 p0 = *(float4*)&pacc[0][t * 4];
            float4 p1 = *(float4*)&pacc[1][t * 4];
            float4 p2 = *(float4*)&pacc[2][t * 4];
            float4 p3 = *(float4*)&pacc[3][t * 4];
            float4 sum = make_float4(p0.x + p1.x + p2.x + p3.x,
                                     p0.y + p1.y + p2.y + p3.y,
                                     p0.z + p1.z + p2.z + p3.z,
                                     p0.w + p1.w + p2.w + p3.w);
            if (g > 0) *(float4*)&vcur[t * 4] = sum;
            else {
                int o = r0 * 256 + t * 4;
                Rh[o + 0] = (f16)sum.x;
                Rh[o + 1] = (f16)sum.y;
                Rh[o + 2] = (f16)sum.z;
                Rh[o + 3] = (f16)sum.w;
            }
        }
        __syncthreads();
    }
}

// ---------------------------------------------------------------------------
// K4: out = R * X via FP16 MFMA (mfma_f32_16x16x32_f16, fp32 accumulate).
// Unchanged (verified correct in rounds 5-6).
// ---------------------------------------------------------------------------
__global__ __launch_bounds__(512) void k_gemm(const f16* __restrict__ Rh,
                                              const float* __restrict__ X,
                                              float* __restrict__ out) {
    __shared__ float Xf[256][32];                    // 32 KB fp32 staging
    __shared__ __align__(16) f16 Xh[32 * 256];       // 16 KB fp16 k-major
    int t  = threadIdx.x;
    int w  = t >> 6;                                 // wave 0..7
    int l  = t & 63;
    int n0 = blockIdx.x * 32;

    // phase A: global -> Xf (coalesced float4)
#pragma unroll
    for (int p = 0; p < 4; ++p) {
        int idx = t + 512 * p;                       // 0..2047
        int n4  = idx & 7;
        int k   = idx >> 3;
        *(float4*)&Xf[k][n4 * 4] =
            *(const float4*)(X + (size_t)k * NB + n0 + n4 * 4);
    }
    __syncthreads();

    // phase B: Xf -> fp16 k-major swizzled Xh
    {
        int n  = t & 31;
        int k0 = (t >> 5) * 16;
        f16x8 h0, h1;
#pragma unroll
        for (int u = 0; u < 8; ++u) h0[u] = (f16)Xf[k0 + u][n];
#pragma unroll
        for (int u = 0; u < 8; ++u) h1[u] = (f16)Xf[k0 + 8 + u][n];
        int xv = (n & 7) * 8;
        *(f16x8*)&Xh[n * 256 + ((k0    ) ^ xv)] = h0;
        *(f16x8*)&Xh[n * 256 + ((k0 + 8) ^ xv)] = h1;
    }
    __syncthreads();

    f32x4 acc[2][2];
#pragma unroll
    for (int r = 0; r < 2; ++r)
#pragma unroll
        for (int c = 0; c < 2; ++c) acc[r][c] = (f32x4){0.f, 0.f, 0.f, 0.f};

    int lm = l & 15;
    int g  = l >> 4;
    int xv = (lm & 7) * 8;
#pragma unroll
    for (int s = 0; s < 8; ++s) {
        int koff = s * 32 + 8 * g;
        f16x8 a0 = *(const f16x8*)(Rh + (32 * w + lm) * 256 + koff);
        f16x8 a1 = *(const f16x8*)(Rh + (32 * w + 16 + lm) * 256 + koff);
        f16x8 b0 = *(const f16x8*)&Xh[lm * 256        + (koff ^ xv)];
        f16x8 b1 = *(const f16x8*)&Xh[(16 + lm) * 256 + (koff ^ xv)];
        acc[0][0] = __builtin_amdgcn_mfma_f32_16x16x32_f16(a0, b0, acc[0][0], 0, 0, 0);
        acc[0][1] = __builtin_amdgcn_mfma_f32_16x16x32_f16(a0, b1, acc[0][1], 0, 0, 0);
        acc[1][0] = __builtin_amdgcn_mfma_f32_16x16x32_f16(a1, b0, acc[1][0], 0, 0, 0);
        acc[1][1] = __builtin_amdgcn_mfma_f32_16x16x32_f16(a1, b1, acc[1][1], 0, 0, 0);
    }

    // C/D layout: col = lane&15, row = (lane>>4)*4 + reg
#pragma unroll
    for (int r = 0; r < 2; ++r)
#pragma unroll
        for (int c = 0; c < 2; ++c)
#pragma unroll
            for (int q = 0; q < 4; ++q)
                out[(size_t)(32 * w + 16 * r + 4 * g + q) * NB + n0 + 16 * c + lm] =
                    acc[r][c][q];
}

// ---------------------------------------------------------------------------
extern "C" void kernel_launch(void* const* d_in, const int* in_sizes, int n_in,
                              void* d_out, int out_size, void* d_ws, size_t ws_size,
                              hipStream_t stream) {
    const float* X      = (const float*)d_in[0];
    const float* thetas = (const float*)d_in[1];
    float* out = (float*)d_out;
    char*  ws  = (char*)d_ws;

    float2* cs   = (float2*)ws;
    float4* csf4 = (float4*)ws;
    float*  Rg   = (float*)(ws + 270336);
    f16*    Rh   = (f16*)(ws + 1318912);

    k_prep  <<<dim3(132),    dim3(256), 0, stream>>>(thetas, cs);
    k_rot   <<<dim3(256, 4), dim3(64),  0, stream>>>(csf4, Rg);
    k_merge4<<<dim3(256),    dim3(256), 0, stream>>>(Rg, Rh);
    k_gemm  <<<dim3(256),    dim3(512), 0, stream>>>(Rh, X, out);
}